// Round 3
// baseline (304.959 us; speedup 1.0000x reference)
//
#include <hip/hip_runtime.h>
#include <hip/hip_bf16.h>

#define V_ 32000
#define E_ 100
#define H_ 128
#define B_ 1024
#define T_ 256

typedef float f32x4 __attribute__((ext_vector_type(4)));
typedef __bf16 bf16x8 __attribute__((ext_vector_type(8)));
typedef __bf16 bf16x4 __attribute__((ext_vector_type(4)));

__device__ __forceinline__ f32x4 mfma16(bf16x8 a, bf16x8 b, f32x4 c) {
    return __builtin_amdgcn_mfma_f32_16x16x32_bf16(a, b, c, 0, 0, 0);
}

__device__ __forceinline__ void split_bf16(float v, __bf16& hi, __bf16& lo) {
    hi = (__bf16)v;
    lo = (__bf16)(v - (float)hi);
}

__device__ __forceinline__ void cvt8(f32x4 p0, f32x4 p1, bf16x8& hi, bf16x8& lo) {
#pragma unroll
    for (int e = 0; e < 4; ++e) {
        __bf16 h1, l1; split_bf16(p0[e], h1, l1);
        hi[e] = h1; lo[e] = l1;
        __bf16 h2, l2; split_bf16(p1[e], h2, l2);
        hi[4 + e] = h2; lo[4 + e] = l2;
    }
}

// Granule layout (per 128x128 matrix): linear granule g = tile*256 + kc*64 +
// sub*16 + c ; holds elements [row = tile*16 + c][k = (kc*4+sub)*8 .. +8).
// Main-loop read for (tile,kc) at lane l: byte offset tile*4096 + kc*1024 + l*16
// -> contiguous 1KB per wave-read, zero bank conflicts. Staging writes at byte
// g*16 -> sequential, zero conflicts.

// ---------------------------------------------------------------------------
// K1: xp[tq][b][h] = emb[x[b,t]] @ W_ih^T + b_ih + b_hh  (K=100 padded to 128)
// Operand-swapped: A = W_ih (M=h), B = emb^T (col=batch) -> f32x4 stores along h.
// grid: (B/128, len) ; block 512 (8 waves).
// ---------------------------------------------------------------------------
__global__ __launch_bounds__(512, 1) void k1_xproj(
    const int* __restrict__ x, const float* __restrict__ emb,
    const float* __restrict__ Wih, const float* __restrict__ bih,
    const float* __restrict__ bhh, float* __restrict__ xp, int t0)
{
    __shared__ __align__(16) __bf16 Ah[16384], Al[16384], Bh[16384], Bl[16384];
    __shared__ int xidx[128];
    const int tid = threadIdx.x;
    const int b0 = blockIdx.x * 128;
    const int tq = blockIdx.y;
    const int t = t0 + tq;

    if (tid < 128) xidx[tid] = x[(size_t)(b0 + tid) * T_ + t];

    // stage A = W_ih granules (rows = h, k-len 100 padded)
    for (int g = tid; g < 2048; g += 512) {
        int row = ((g >> 8) << 4) | (g & 15);
        int k0 = ((g >> 4) & 15) * 8;
        const float* src = Wih + (size_t)row * E_ + k0;
        f32x4 z = {0.f, 0.f, 0.f, 0.f};
        f32x4 p0 = (k0 + 4 <= E_) ? *(const f32x4*)src : z;
        f32x4 p1 = (k0 + 8 <= E_) ? *(const f32x4*)(src + 4) : z;
        bf16x8 hi, lo; cvt8(p0, p1, hi, lo);
        *(bf16x8*)&Ah[g * 8] = hi; *(bf16x8*)&Al[g * 8] = lo;
    }
    __syncthreads();   // covers xidx too
    // stage B = gathered emb rows (col dim = batch)
    for (int g = tid; g < 2048; g += 512) {
        int row = ((g >> 8) << 4) | (g & 15);
        int k0 = ((g >> 4) & 15) * 8;
        const float* src = emb + (size_t)xidx[row] * E_ + k0;
        f32x4 z = {0.f, 0.f, 0.f, 0.f};
        f32x4 p0 = (k0 + 4 <= E_) ? *(const f32x4*)src : z;
        f32x4 p1 = (k0 + 8 <= E_) ? *(const f32x4*)(src + 4) : z;
        bf16x8 hi, lo; cvt8(p0, p1, hi, lo);
        *(bf16x8*)&Bh[g * 8] = hi; *(bf16x8*)&Bl[g * 8] = lo;
    }
    __syncthreads();

    const int lane = tid & 63, w = tid >> 6;
    const int sub = lane >> 4, rc = lane & 15;
    const int mt0 = (w & 3) * 2, nt0 = (w >> 2) * 4;
    f32x4 acc[2][4];
#pragma unroll
    for (int m = 0; m < 2; ++m)
#pragma unroll
        for (int n = 0; n < 4; ++n) acc[m][n] = (f32x4){0.f, 0.f, 0.f, 0.f};

#pragma unroll
    for (int kc = 0; kc < 4; ++kc) {
        bf16x8 a_h[2], a_l[2];
#pragma unroll
        for (int m = 0; m < 2; ++m) {
            int off = (mt0 + m) * 2048 + kc * 512 + lane * 8;
            a_h[m] = *(const bf16x8*)&Ah[off];
            a_l[m] = *(const bf16x8*)&Al[off];
        }
#pragma unroll
        for (int n = 0; n < 4; ++n) {
            int off = (nt0 + n) * 2048 + kc * 512 + lane * 8;
            bf16x8 b_h = *(const bf16x8*)&Bh[off];
            bf16x8 b_l = *(const bf16x8*)&Bl[off];
#pragma unroll
            for (int m = 0; m < 2; ++m) {
                acc[m][n] = mfma16(a_h[m], b_h, acc[m][n]);
                acc[m][n] = mfma16(a_l[m], b_h, acc[m][n]);
                acc[m][n] = mfma16(a_h[m], b_l, acc[m][n]);
            }
        }
    }
    f32x4 bias4[2];
#pragma unroll
    for (int m = 0; m < 2; ++m) {
        int h0 = (mt0 + m) * 16 + sub * 4;
        bias4[m] = *(const f32x4*)&bih[h0] + *(const f32x4*)&bhh[h0];
    }
#pragma unroll
    for (int n = 0; n < 4; ++n) {
#pragma unroll
        for (int m = 0; m < 2; ++m) {
            f32x4 v = acc[m][n] + bias4[m];
            float* dst = xp + ((size_t)tq * B_ + b0 + (nt0 + n) * 16 + rc) * H_
                            + (mt0 + m) * 16 + sub * 4;
            *(f32x4*)dst = v;
        }
    }
}

// ---------------------------------------------------------------------------
// K2: RNN scan. 64 blocks x 16 batch; 4 waves (1/SIMD); wave w owns hidden
// rows [32w, 32w+32). Z = W_hh · h^T; h exchanged via conflict-free granule
// LDS (lane l reads byte l*16 + kc*1024). 2-deep xt prefetch. 1 barrier/step.
// ---------------------------------------------------------------------------
__global__ __launch_bounds__(256, 1) void k2_rnn(
    const float* __restrict__ xp, const float* __restrict__ Whh,
    float* __restrict__ hstate, int t0, int len)
{
    __shared__ __align__(16) __bf16 Hg[2][4096];   // [p][ hi:0..2047 | lo:2048.. ]
    const int tid = threadIdx.x;
    const int lane = tid & 63, w = tid >> 6;
    const int b0 = blockIdx.x * 16;
    const int sub = lane >> 4, c = lane & 15;

    // A fragments: W_hh rows w*32 + m*16 + c, loop-invariant, in registers
    bf16x8 wah[2][4], wal[2][4];
#pragma unroll
    for (int m = 0; m < 2; ++m)
#pragma unroll
        for (int kc = 0; kc < 4; ++kc) {
            const float* src = Whh + (size_t)(w * 32 + m * 16 + c) * H_ + kc * 32 + sub * 8;
            cvt8(*(const f32x4*)src, *(const f32x4*)(src + 4), wah[m][kc], wal[m][kc]);
        }

    if (t0 == 0) {
        bf16x8 z8;
#pragma unroll
        for (int e = 0; e < 8; ++e) z8[e] = (__bf16)0.0f;
        *(bf16x8*)&Hg[0][tid * 8] = z8;
        *(bf16x8*)&Hg[0][2048 + tid * 8] = z8;
    } else {
        int kc = tid >> 6, sb = (tid >> 4) & 3, cc = tid & 15;
        const float* src = hstate + (size_t)(b0 + cc) * H_ + kc * 32 + sb * 8;
        bf16x8 hi, lo;
        cvt8(*(const f32x4*)src, *(const f32x4*)(src + 4), hi, lo);
        *(bf16x8*)&Hg[0][tid * 8] = hi;
        *(bf16x8*)&Hg[0][2048 + tid * 8] = lo;
    }
    __syncthreads();

    const float* xb = xp + (size_t)(b0 + c) * H_ + w * 32 + sub * 4;
    const size_t xstep = (size_t)B_ * H_;
    f32x4 x0[2], x1[2], x2[2];
    x0[0] = *(const f32x4*)(xb);
    x0[1] = *(const f32x4*)(xb + 16);
    {
        size_t t1i = (len > 1) ? 1 : 0;
        x1[0] = *(const f32x4*)(xb + t1i * xstep);
        x1[1] = *(const f32x4*)(xb + t1i * xstep + 16);
    }

    int p = 0;
    for (int tq = 0; tq < len; ++tq) {
        size_t tn = (tq + 2 < len) ? (size_t)(tq + 2) : (size_t)(len - 1);
        x2[0] = *(const f32x4*)(xb + tn * xstep);
        x2[1] = *(const f32x4*)(xb + tn * xstep + 16);

        const __bf16* Hp = &Hg[p][0];
        bf16x8 bh[4], bl[4];
#pragma unroll
        for (int kc = 0; kc < 4; ++kc) {
            bh[kc] = *(const bf16x8*)(Hp + kc * 512 + lane * 8);
            bl[kc] = *(const bf16x8*)(Hp + 2048 + kc * 512 + lane * 8);
        }
        f32x4 a00 = x0[0], a01 = {0.f, 0.f, 0.f, 0.f};
        f32x4 a10 = x0[1], a11 = {0.f, 0.f, 0.f, 0.f};
#pragma unroll
        for (int kc = 0; kc < 4; ++kc) {
            if (kc & 1) {
                a01 = mfma16(wah[0][kc], bh[kc], a01);
                a11 = mfma16(wah[1][kc], bh[kc], a11);
                a01 = mfma16(wal[0][kc], bh[kc], a01);
                a11 = mfma16(wal[1][kc], bh[kc], a11);
                a01 = mfma16(wah[0][kc], bl[kc], a01);
                a11 = mfma16(wah[1][kc], bl[kc], a11);
            } else {
                a00 = mfma16(wah[0][kc], bh[kc], a00);
                a10 = mfma16(wah[1][kc], bh[kc], a10);
                a00 = mfma16(wal[0][kc], bh[kc], a00);
                a10 = mfma16(wal[1][kc], bh[kc], a10);
                a00 = mfma16(wah[0][kc], bl[kc], a00);
                a10 = mfma16(wah[1][kc], bl[kc], a10);
            }
        }
        __bf16* Hw = &Hg[p ^ 1][0];
#pragma unroll
        for (int m = 0; m < 2; ++m) {
            f32x4 s = (m == 0) ? (a00 + a01) : (a10 + a11);
            f32x4 hv; bf16x4 hi4, lo4;
#pragma unroll
            for (int r = 0; r < 4; ++r) {
                float e;
                asm("v_exp_f32 %0, %1" : "=v"(e) : "v"(s[r] * 2.8853900817779268f));
                float ep1 = e + 1.0f;
                float rcp;
                asm("v_rcp_f32 %0, %1" : "=v"(rcp) : "v"(ep1));
                float h = 1.0f - 2.0f * rcp;
                hv[r] = h;
                __bf16 hb = (__bf16)h;
                hi4[r] = hb;
                lo4[r] = (__bf16)(h - (float)hb);
            }
            if (tq == len - 1)
                *(f32x4*)&hstate[(size_t)(b0 + c) * H_ + w * 32 + m * 16 + sub * 4] = hv;
            // hidden index i = w*32 + m*16 + sub*4 + r  ->  granule (kc'=w,
            // sub'=(2m+(sub>>1))&3, c, e'=(sub&1)*4+r)
            int subp = (2 * m + (sub >> 1)) & 3;
            int wb = ((w * 4 + subp) * 16 + c) * 8 + (sub & 1) * 4;
            *(bf16x4*)&Hw[wb] = hi4;
            *(bf16x4*)&Hw[2048 + wb] = lo4;
        }
        asm volatile("s_waitcnt lgkmcnt(0)" ::: "memory");
        __builtin_amdgcn_s_barrier();
        __builtin_amdgcn_sched_barrier(0);
        p ^= 1;
        x0[0] = x1[0]; x0[1] = x1[1];
        x1[0] = x2[0]; x1[1] = x2[1];
    }
}

// ---------------------------------------------------------------------------
// K3: out[b][v] = h[b] @ W_fc[v]^T + b_fc[v]. Operand-swapped: A = W_fc (M=v),
// B = h^T (col=batch) -> f32x4 stores along v. grid: (V/128, B/128); block 512.
// ---------------------------------------------------------------------------
__global__ __launch_bounds__(512, 1) void k3_head(
    const float* __restrict__ hstate, const float* __restrict__ Wfc,
    const float* __restrict__ bfc, float* __restrict__ out)
{
    __shared__ __align__(16) __bf16 Ah[16384], Al[16384], Bh[16384], Bl[16384];
    const int tid = threadIdx.x;
    const int v0 = blockIdx.x * 128;
    const int b0 = blockIdx.y * 128;

    // stage A = W_fc granules (rows = v), K=128 exact
    for (int g = tid; g < 2048; g += 512) {
        int row = ((g >> 8) << 4) | (g & 15);
        int k0 = ((g >> 4) & 15) * 8;
        const float* src = Wfc + (size_t)(v0 + row) * H_ + k0;
        bf16x8 hi, lo;
        cvt8(*(const f32x4*)src, *(const f32x4*)(src + 4), hi, lo);
        *(bf16x8*)&Ah[g * 8] = hi; *(bf16x8*)&Al[g * 8] = lo;
    }
    // stage B = h granules (col dim = batch)
    for (int g = tid; g < 2048; g += 512) {
        int row = ((g >> 8) << 4) | (g & 15);
        int k0 = ((g >> 4) & 15) * 8;
        const float* src = hstate + (size_t)(b0 + row) * H_ + k0;
        bf16x8 hi, lo;
        cvt8(*(const f32x4*)src, *(const f32x4*)(src + 4), hi, lo);
        *(bf16x8*)&Bh[g * 8] = hi; *(bf16x8*)&Bl[g * 8] = lo;
    }
    __syncthreads();

    const int lane = tid & 63, w = tid >> 6;
    const int sub = lane >> 4, rc = lane & 15;
    const int mt0 = (w & 3) * 2, nt0 = (w >> 2) * 4;
    f32x4 acc[2][4];
#pragma unroll
    for (int m = 0; m < 2; ++m)
#pragma unroll
        for (int n = 0; n < 4; ++n) acc[m][n] = (f32x4){0.f, 0.f, 0.f, 0.f};

#pragma unroll
    for (int kc = 0; kc < 4; ++kc) {
        bf16x8 a_h[2], a_l[2];
#pragma unroll
        for (int m = 0; m < 2; ++m) {
            int off = (mt0 + m) * 2048 + kc * 512 + lane * 8;
            a_h[m] = *(const bf16x8*)&Ah[off];
            a_l[m] = *(const bf16x8*)&Al[off];
        }
#pragma unroll
        for (int n = 0; n < 4; ++n) {
            int off = (nt0 + n) * 2048 + kc * 512 + lane * 8;
            bf16x8 b_h = *(const bf16x8*)&Bh[off];
            bf16x8 b_l = *(const bf16x8*)&Bl[off];
#pragma unroll
            for (int m = 0; m < 2; ++m) {
                acc[m][n] = mfma16(a_h[m], b_h, acc[m][n]);
                acc[m][n] = mfma16(a_l[m], b_h, acc[m][n]);
                acc[m][n] = mfma16(a_h[m], b_l, acc[m][n]);
            }
        }
    }
    f32x4 bias4[2];
#pragma unroll
    for (int m = 0; m < 2; ++m)
        bias4[m] = *(const f32x4*)&bfc[v0 + (mt0 + m) * 16 + sub * 4];
#pragma unroll
    for (int n = 0; n < 4; ++n) {
#pragma unroll
        for (int m = 0; m < 2; ++m) {
            f32x4 v = acc[m][n] + bias4[m];
            float* dst = out + (size_t)(b0 + (nt0 + n) * 16 + rc) * V_
                             + v0 + (mt0 + m) * 16 + sub * 4;
            *(f32x4*)dst = v;
        }
    }
}

extern "C" void kernel_launch(void* const* d_in, const int* in_sizes, int n_in,
                              void* d_out, int out_size, void* d_ws, size_t ws_size,
                              hipStream_t stream) {
    const int*   x   = (const int*)d_in[0];
    const float* emb = (const float*)d_in[1];
    const float* Wih = (const float*)d_in[2];
    const float* Whh = (const float*)d_in[3];
    const float* bih = (const float*)d_in[4];
    const float* bhh = (const float*)d_in[5];
    const float* Wfc = (const float*)d_in[6];
    const float* bfc = (const float*)d_in[7];
    float* out = (float*)d_out;

    const size_t per_t  = (size_t)B_ * H_ * sizeof(float);  // 512 KB / timestep
    const size_t hbytes = (size_t)B_ * H_ * sizeof(float);

    float* hstate = (float*)d_ws;
    float* xp;
    int Tc;
    if (ws_size >= hbytes + per_t) {
        xp = hstate + (size_t)B_ * H_;
        size_t tcap = (ws_size - hbytes) / per_t;
        Tc = tcap >= (size_t)T_ ? T_ : (int)tcap;
    } else {
        // fallback: stage xp chunks in d_out (250 timesteps fit); K3 overwrites last
        xp = out;
        Tc = 250;
    }

    for (int t0 = 0; t0 < T_; t0 += Tc) {
        int len = (T_ - t0) < Tc ? (T_ - t0) : Tc;
        k1_xproj<<<dim3(8, len), 512, 0, stream>>>(x, emb, Wih, bih, bhh, xp, t0);
        k2_rnn<<<dim3(64), 256, 0, stream>>>(xp, Whh, hstate, t0, len);
    }
    k3_head<<<dim3(250, 8), 512, 0, stream>>>(hstate, Wfc, bfc, out);
}

// Round 4
// 261.537 us; speedup vs baseline: 1.1660x; 1.1660x over previous
//
#include <hip/hip_runtime.h>
#include <hip/hip_bf16.h>

#define V_ 32000
#define E_ 100
#define H_ 128
#define B_ 1024
#define T_ 256

typedef float f32x4 __attribute__((ext_vector_type(4)));
typedef __bf16 bf16x8 __attribute__((ext_vector_type(8)));
typedef __bf16 bf16x4 __attribute__((ext_vector_type(4)));

__device__ __forceinline__ f32x4 mfma16(bf16x8 a, bf16x8 b, f32x4 c) {
    return __builtin_amdgcn_mfma_f32_16x16x32_bf16(a, b, c, 0, 0, 0);
}

__device__ __forceinline__ void split_bf16(float v, __bf16& hi, __bf16& lo) {
    hi = (__bf16)v;
    lo = (__bf16)(v - (float)hi);
}

__device__ __forceinline__ void cvt8(f32x4 p0, f32x4 p1, bf16x8& hi, bf16x8& lo) {
#pragma unroll
    for (int e = 0; e < 4; ++e) {
        __bf16 h1, l1; split_bf16(p0[e], h1, l1);
        hi[e] = h1; lo[e] = l1;
        __bf16 h2, l2; split_bf16(p1[e], h2, l2);
        hi[4 + e] = h2; lo[4 + e] = l2;
    }
}

// Granule layout (per 128x128 matrix): linear granule g = tile*256 + kc*64 +
// sub*16 + c ; holds elements [row = tile*16 + c][k = (kc*4+sub)*8 .. +8).
// Main-loop read for (tile,kc) at lane l: byte offset tile*4096 + kc*1024 + l*16
// -> contiguous 1KB per wave-read, zero bank conflicts. Staging writes at byte
// g*16 -> sequential, zero conflicts.

// ---------------------------------------------------------------------------
// K1: xp[tq][b][h] = emb[x[b,t]] @ W_ih^T + b_ih + b_hh  (K=100 padded to 128)
// Operand-swapped: A = W_ih (M=h), B = emb^T (col=batch) -> f32x4 stores along h.
// grid: (B/128, len) ; block 512 (8 waves).
// ---------------------------------------------------------------------------
__global__ __launch_bounds__(512, 1) void k1_xproj(
    const int* __restrict__ x, const float* __restrict__ emb,
    const float* __restrict__ Wih, const float* __restrict__ bih,
    const float* __restrict__ bhh, float* __restrict__ xp, int t0)
{
    __shared__ __align__(16) __bf16 Ah[16384], Al[16384], Bh[16384], Bl[16384];
    __shared__ int xidx[128];
    const int tid = threadIdx.x;
    const int b0 = blockIdx.x * 128;
    const int tq = blockIdx.y;
    const int t = t0 + tq;

    if (tid < 128) xidx[tid] = x[(size_t)(b0 + tid) * T_ + t];

    // stage A = W_ih granules (rows = h, k-len 100 padded)
    for (int g = tid; g < 2048; g += 512) {
        int row = ((g >> 8) << 4) | (g & 15);
        int k0 = ((g >> 4) & 15) * 8;
        const float* src = Wih + (size_t)row * E_ + k0;
        f32x4 z = {0.f, 0.f, 0.f, 0.f};
        f32x4 p0 = (k0 + 4 <= E_) ? *(const f32x4*)src : z;
        f32x4 p1 = (k0 + 8 <= E_) ? *(const f32x4*)(src + 4) : z;
        bf16x8 hi, lo; cvt8(p0, p1, hi, lo);
        *(bf16x8*)&Ah[g * 8] = hi; *(bf16x8*)&Al[g * 8] = lo;
    }
    __syncthreads();   // covers xidx too
    // stage B = gathered emb rows (col dim = batch)
    for (int g = tid; g < 2048; g += 512) {
        int row = ((g >> 8) << 4) | (g & 15);
        int k0 = ((g >> 4) & 15) * 8;
        const float* src = emb + (size_t)xidx[row] * E_ + k0;
        f32x4 z = {0.f, 0.f, 0.f, 0.f};
        f32x4 p0 = (k0 + 4 <= E_) ? *(const f32x4*)src : z;
        f32x4 p1 = (k0 + 8 <= E_) ? *(const f32x4*)(src + 4) : z;
        bf16x8 hi, lo; cvt8(p0, p1, hi, lo);
        *(bf16x8*)&Bh[g * 8] = hi; *(bf16x8*)&Bl[g * 8] = lo;
    }
    __syncthreads();

    const int lane = tid & 63, w = tid >> 6;
    const int sub = lane >> 4, rc = lane & 15;
    const int mt0 = (w & 3) * 2, nt0 = (w >> 2) * 4;
    f32x4 acc[2][4];
#pragma unroll
    for (int m = 0; m < 2; ++m)
#pragma unroll
        for (int n = 0; n < 4; ++n) acc[m][n] = (f32x4){0.f, 0.f, 0.f, 0.f};

#pragma unroll
    for (int kc = 0; kc < 4; ++kc) {
        bf16x8 a_h[2], a_l[2];
#pragma unroll
        for (int m = 0; m < 2; ++m) {
            int off = (mt0 + m) * 2048 + kc * 512 + lane * 8;
            a_h[m] = *(const bf16x8*)&Ah[off];
            a_l[m] = *(const bf16x8*)&Al[off];
        }
#pragma unroll
        for (int n = 0; n < 4; ++n) {
            int off = (nt0 + n) * 2048 + kc * 512 + lane * 8;
            bf16x8 b_h = *(const bf16x8*)&Bh[off];
            bf16x8 b_l = *(const bf16x8*)&Bl[off];
#pragma unroll
            for (int m = 0; m < 2; ++m) {
                acc[m][n] = mfma16(a_h[m], b_h, acc[m][n]);
                acc[m][n] = mfma16(a_l[m], b_h, acc[m][n]);
                acc[m][n] = mfma16(a_h[m], b_l, acc[m][n]);
            }
        }
    }
    f32x4 bias4[2];
#pragma unroll
    for (int m = 0; m < 2; ++m) {
        int h0 = (mt0 + m) * 16 + sub * 4;
        bias4[m] = *(const f32x4*)&bih[h0] + *(const f32x4*)&bhh[h0];
    }
#pragma unroll
    for (int n = 0; n < 4; ++n) {
#pragma unroll
        for (int m = 0; m < 2; ++m) {
            f32x4 v = acc[m][n] + bias4[m];
            float* dst = xp + ((size_t)tq * B_ + b0 + (nt0 + n) * 16 + rc) * H_
                            + (mt0 + m) * 16 + sub * 4;
            *(f32x4*)dst = v;
        }
    }
}

// ---------------------------------------------------------------------------
// K2: RNN scan. 64 blocks x 16 batch; 8 waves (2/SIMD); wave w owns hidden
// rows [16w, 16w+16). 2-term split: W_hh hi/lo in registers, h carried as
// plain bf16 in conflict-free granule LDS (read byte kc*1024 + lane*16).
// 3-deep xt prefetch; 4 MFMA chains of depth 2; 1 barrier/step.
// ---------------------------------------------------------------------------
__global__ __launch_bounds__(512, 1) void k2_rnn(
    const float* __restrict__ xp, const float* __restrict__ Whh,
    float* __restrict__ hstate, int t0, int len)
{
    __shared__ __align__(16) __bf16 Hg[2][2048];
    const int tid = threadIdx.x;
    const int lane = tid & 63, w = tid >> 6;
    const int b0 = blockIdx.x * 16;
    const int sub = lane >> 4, c = lane & 15;

    // A fragments: W_hh rows w*16 + c, split hi/lo; loop-invariant
    bf16x8 wah[4], wal[4];
#pragma unroll
    for (int kc = 0; kc < 4; ++kc) {
        const float* src = Whh + (size_t)(w * 16 + c) * H_ + kc * 32 + sub * 8;
        cvt8(*(const f32x4*)src, *(const f32x4*)(src + 4), wah[kc], wal[kc]);
    }

    if (t0 == 0) {
        if (tid < 256) {
            bf16x8 z8;
#pragma unroll
            for (int e = 0; e < 8; ++e) z8[e] = (__bf16)0.0f;
            *(bf16x8*)&Hg[0][tid * 8] = z8;
        }
    } else {
        // element range [tid*4, tid*4+4) of granule layout
        int kcq = tid >> 7, sbq = (tid >> 5) & 3, cq = (tid >> 1) & 15;
        int i = kcq * 32 + sbq * 8 + (tid & 1) * 4;
        f32x4 v = *(const f32x4*)&hstate[(size_t)(b0 + cq) * H_ + i];
        bf16x4 b4;
#pragma unroll
        for (int r = 0; r < 4; ++r) b4[r] = (__bf16)v[r];
        *(bf16x4*)&Hg[0][tid * 4] = b4;
    }
    __syncthreads();

    const int i0 = w * 16 + sub * 4;            // this lane's 4 hidden-out rows
    const float* xb = xp + (size_t)(b0 + c) * H_ + i0;
    const size_t xstep = (size_t)B_ * H_;
    // 3-deep prefetch ring
    f32x4 xr0, xr1, xr2, xr3;
    xr0 = *(const f32x4*)(xb);
    {
        size_t i1 = (len > 1) ? 1 : 0, i2 = (len > 2) ? 2 : (size_t)(len - 1);
        xr1 = *(const f32x4*)(xb + i1 * xstep);
        xr2 = *(const f32x4*)(xb + i2 * xstep);
    }

    // LDS write position for hidden rows i0..i0+3, col c (granule layout)
    const int wb = (((w >> 1) * 64 + ((w & 1) * 2 + (sub >> 1)) * 16 + c) << 3)
                 + (sub & 1) * 4;

    int p = 0;
    for (int tq = 0; tq < len; ++tq) {
        size_t tn = (tq + 3 < len) ? (size_t)(tq + 3) : (size_t)(len - 1);
        xr3 = *(const f32x4*)(xb + tn * xstep);

        const __bf16* Hp = &Hg[p][0];
        bf16x8 hb0 = *(const bf16x8*)(Hp + 0 * 512 + lane * 8);
        bf16x8 hb1 = *(const bf16x8*)(Hp + 1 * 512 + lane * 8);
        bf16x8 hb2 = *(const bf16x8*)(Hp + 2 * 512 + lane * 8);
        bf16x8 hb3 = *(const bf16x8*)(Hp + 3 * 512 + lane * 8);

        f32x4 zz = {0.f, 0.f, 0.f, 0.f};
        f32x4 a0 = mfma16(wah[0], hb0, xr0);
        f32x4 a1 = mfma16(wal[0], hb0, zz);
        f32x4 a2 = mfma16(wah[1], hb1, zz);
        f32x4 a3 = mfma16(wal[1], hb1, zz);
        a0 = mfma16(wah[2], hb2, a0);
        a1 = mfma16(wal[2], hb2, a1);
        a2 = mfma16(wah[3], hb3, a2);
        a3 = mfma16(wal[3], hb3, a3);
        f32x4 s = (a0 + a1) + (a2 + a3);

        // fast tanh: 1 - 2/(exp2(2x*log2e)+1)
        f32x4 hv; bf16x4 h4;
#pragma unroll
        for (int r = 0; r < 4; ++r) {
            float e;
            asm("v_exp_f32 %0, %1" : "=v"(e) : "v"(s[r] * 2.8853900817779268f));
            float ep1 = e + 1.0f;
            float rcp;
            asm("v_rcp_f32 %0, %1" : "=v"(rcp) : "v"(ep1));
            float h = 1.0f - 2.0f * rcp;
            hv[r] = h;
            h4[r] = (__bf16)h;
        }
        if (tq == len - 1)
            *(f32x4*)&hstate[(size_t)(b0 + c) * H_ + i0] = hv;

        *(bf16x4*)&Hg[p ^ 1][wb] = h4;

        asm volatile("s_waitcnt lgkmcnt(0)" ::: "memory");
        __builtin_amdgcn_s_barrier();
        __builtin_amdgcn_sched_barrier(0);
        p ^= 1;
        xr0 = xr1; xr1 = xr2; xr2 = xr3;
    }
}

// ---------------------------------------------------------------------------
// K3: out[b][v] = h[b] @ W_fc[v]^T + b_fc[v]. Operand-swapped: A = W_fc (M=v),
// B = h^T (col=batch) -> f32x4 stores along v. grid: (V/128, B/128); block 512.
// ---------------------------------------------------------------------------
__global__ __launch_bounds__(512, 1) void k3_head(
    const float* __restrict__ hstate, const float* __restrict__ Wfc,
    const float* __restrict__ bfc, float* __restrict__ out)
{
    __shared__ __align__(16) __bf16 Ah[16384], Al[16384], Bh[16384], Bl[16384];
    const int tid = threadIdx.x;
    const int v0 = blockIdx.x * 128;
    const int b0 = blockIdx.y * 128;

    // stage A = W_fc granules (rows = v), K=128 exact
    for (int g = tid; g < 2048; g += 512) {
        int row = ((g >> 8) << 4) | (g & 15);
        int k0 = ((g >> 4) & 15) * 8;
        const float* src = Wfc + (size_t)(v0 + row) * H_ + k0;
        bf16x8 hi, lo;
        cvt8(*(const f32x4*)src, *(const f32x4*)(src + 4), hi, lo);
        *(bf16x8*)&Ah[g * 8] = hi; *(bf16x8*)&Al[g * 8] = lo;
    }
    // stage B = h granules (col dim = batch)
    for (int g = tid; g < 2048; g += 512) {
        int row = ((g >> 8) << 4) | (g & 15);
        int k0 = ((g >> 4) & 15) * 8;
        const float* src = hstate + (size_t)(b0 + row) * H_ + k0;
        bf16x8 hi, lo;
        cvt8(*(const f32x4*)src, *(const f32x4*)(src + 4), hi, lo);
        *(bf16x8*)&Bh[g * 8] = hi; *(bf16x8*)&Bl[g * 8] = lo;
    }
    __syncthreads();

    const int lane = tid & 63, w = tid >> 6;
    const int sub = lane >> 4, rc = lane & 15;
    const int mt0 = (w & 3) * 2, nt0 = (w >> 2) * 4;
    f32x4 acc[2][4];
#pragma unroll
    for (int m = 0; m < 2; ++m)
#pragma unroll
        for (int n = 0; n < 4; ++n) acc[m][n] = (f32x4){0.f, 0.f, 0.f, 0.f};

#pragma unroll
    for (int kc = 0; kc < 4; ++kc) {
        bf16x8 a_h[2], a_l[2];
#pragma unroll
        for (int m = 0; m < 2; ++m) {
            int off = (mt0 + m) * 2048 + kc * 512 + lane * 8;
            a_h[m] = *(const bf16x8*)&Ah[off];
            a_l[m] = *(const bf16x8*)&Al[off];
        }
#pragma unroll
        for (int n = 0; n < 4; ++n) {
            int off = (nt0 + n) * 2048 + kc * 512 + lane * 8;
            bf16x8 b_h = *(const bf16x8*)&Bh[off];
            bf16x8 b_l = *(const bf16x8*)&Bl[off];
#pragma unroll
            for (int m = 0; m < 2; ++m) {
                acc[m][n] = mfma16(a_h[m], b_h, acc[m][n]);
                acc[m][n] = mfma16(a_l[m], b_h, acc[m][n]);
                acc[m][n] = mfma16(a_h[m], b_l, acc[m][n]);
            }
        }
    }
    f32x4 bias4[2];
#pragma unroll
    for (int m = 0; m < 2; ++m)
        bias4[m] = *(const f32x4*)&bfc[v0 + (mt0 + m) * 16 + sub * 4];
#pragma unroll
    for (int n = 0; n < 4; ++n) {
#pragma unroll
        for (int m = 0; m < 2; ++m) {
            f32x4 v = acc[m][n] + bias4[m];
            float* dst = out + (size_t)(b0 + (nt0 + n) * 16 + rc) * V_
                             + v0 + (mt0 + m) * 16 + sub * 4;
            *(f32x4*)dst = v;
        }
    }
}

extern "C" void kernel_launch(void* const* d_in, const int* in_sizes, int n_in,
                              void* d_out, int out_size, void* d_ws, size_t ws_size,
                              hipStream_t stream) {
    const int*   x   = (const int*)d_in[0];
    const float* emb = (const float*)d_in[1];
    const float* Wih = (const float*)d_in[2];
    const float* Whh = (const float*)d_in[3];
    const float* bih = (const float*)d_in[4];
    const float* bhh = (const float*)d_in[5];
    const float* Wfc = (const float*)d_in[6];
    const float* bfc = (const float*)d_in[7];
    float* out = (float*)d_out;

    const size_t per_t  = (size_t)B_ * H_ * sizeof(float);  // 512 KB / timestep
    const size_t hbytes = (size_t)B_ * H_ * sizeof(float);

    float* hstate = (float*)d_ws;
    float* xp;
    int Tc;
    if (ws_size >= hbytes + per_t) {
        xp = hstate + (size_t)B_ * H_;
        size_t tcap = (ws_size - hbytes) / per_t;
        Tc = tcap >= (size_t)T_ ? T_ : (int)tcap;
    } else {
        // fallback: stage xp chunks in d_out (250 timesteps fit); K3 overwrites last
        xp = out;
        Tc = 250;
    }

    for (int t0 = 0; t0 < T_; t0 += Tc) {
        int len = (T_ - t0) < Tc ? (T_ - t0) : Tc;
        k1_xproj<<<dim3(8, len), 512, 0, stream>>>(x, emb, Wih, bih, bhh, xp, t0);
        k2_rnn<<<dim3(64), 512, 0, stream>>>(xp, Whh, hstate, t0, len);
    }
    k3_head<<<dim3(250, 8), 512, 0, stream>>>(hstate, Wfc, bfc, out);
}

// Round 5
// 205.778 us; speedup vs baseline: 1.4820x; 1.2710x over previous
//
#include <hip/hip_runtime.h>
#include <hip/hip_bf16.h>

#define V_ 32000
#define E_ 100
#define H_ 128
#define B_ 1024
#define T_ 256

typedef float f32x4 __attribute__((ext_vector_type(4)));
typedef __bf16 bf16x8 __attribute__((ext_vector_type(8)));
typedef __bf16 bf16x4 __attribute__((ext_vector_type(4)));

__device__ __forceinline__ f32x4 mfma16(bf16x8 a, bf16x8 b, f32x4 c) {
    return __builtin_amdgcn_mfma_f32_16x16x32_bf16(a, b, c, 0, 0, 0);
}

// Granule layout (per 128x128 matrix): granule g holds elements
// [row = (g>>8)*16 + (g&15)][k = ((g>>4)&15)*8 .. +8), stored at elems g*8.
// MFMA frag read for (tile,kc) at lane l: elem off tile*2048 + kc*512 + l*8.

// ---------------------------------------------------------------------------
// K0a: embb[v][k] = bf16(emb[v][k]) zero-padded K 100->128.  grid 4000x256.
// ---------------------------------------------------------------------------
__global__ void k0_emb(const float* __restrict__ emb, __bf16* __restrict__ embb) {
    int i = blockIdx.x * 256 + threadIdx.x;      // one bf16x4 per thread
    int e4 = i * 4;
    int v = e4 >> 7, k = e4 & 127;
    if (v >= V_) return;
    bf16x4 o;
    if (k < E_) {
        f32x4 p = *(const f32x4*)&emb[(size_t)v * E_ + k];
#pragma unroll
        for (int r = 0; r < 4; ++r) o[r] = (__bf16)p[r];
    } else {
#pragma unroll
        for (int r = 0; r < 4; ++r) o[r] = (__bf16)0.0f;
    }
    *(bf16x4*)&embb[(size_t)v * 128 + k] = o;
}

// ---------------------------------------------------------------------------
// K0b: W_ih (128x100 f32) -> granule-layout bf16 (K padded to 128). 1 block.
// ---------------------------------------------------------------------------
__global__ void k0_wih(const float* __restrict__ Wih, __bf16* __restrict__ wihb) {
    int tid = threadIdx.x;
#pragma unroll
    for (int i = 0; i < 4; ++i) {
        int t2 = tid + i * 512;
        int tile = t2 >> 8, row4 = (t2 >> 4) & 15, ch = t2 & 15;
        int grow = tile * 16 + row4;
        int g = tile * 256 + ch * 16 + row4;
        bf16x8 o;
#pragma unroll
        for (int e = 0; e < 8; ++e) {
            int k = ch * 8 + e;
            o[e] = (k < E_) ? (__bf16)Wih[(size_t)grow * E_ + k] : (__bf16)0.0f;
        }
        *(bf16x8*)&wihb[(size_t)g * 8] = o;
    }
}

// ---------------------------------------------------------------------------
// K0c: W_fc (32000x128 f32) -> 250 x granule-layout bf16. grid 250x512.
// Thread mapping gives coalesced 512B row reads.
// ---------------------------------------------------------------------------
__global__ void k0_wfc(const float* __restrict__ Wfc, __bf16* __restrict__ wfcb) {
    int gv = blockIdx.x, tid = threadIdx.x;
#pragma unroll
    for (int i = 0; i < 4; ++i) {
        int t2 = tid + i * 512;
        int tile = t2 >> 8, row4 = (t2 >> 4) & 15, ch = t2 & 15;
        int grow = gv * 128 + tile * 16 + row4;
        int g = tile * 256 + ch * 16 + row4;
        const float* src = Wfc + (size_t)grow * H_ + ch * 8;
        f32x4 p0 = *(const f32x4*)src, p1 = *(const f32x4*)(src + 4);
        bf16x8 o;
#pragma unroll
        for (int e = 0; e < 4; ++e) {
            o[e] = (__bf16)p0[e];
            o[4 + e] = (__bf16)p1[e];
        }
        *(bf16x8*)&wfcb[(size_t)gv * 16384 + g * 8] = o;
    }
}

// ---------------------------------------------------------------------------
// K1: xpb[t][b][h] = bf16(emb[x[b,t]] @ W_ih^T + b_ih + b_hh). LDS-free,
// 1-term. A=W_ih frags in regs (once); B=emb frags gathered per t.
// grid (8 batch-blocks, 64 t-blocks), 4 t per block, 512 thr.
// ---------------------------------------------------------------------------
__global__ __launch_bounds__(512, 4) void k1_xproj(
    const int* __restrict__ x, const __bf16* __restrict__ embb,
    const __bf16* __restrict__ wihb, const float* __restrict__ bih,
    const float* __restrict__ bhh, __bf16* __restrict__ xpb)
{
    const int tid = threadIdx.x;
    const int lane = tid & 63, w = tid >> 6;
    const int b0 = blockIdx.x * 128;
    const int sub = lane >> 4, rc = lane & 15;
    const int mt0 = (w & 3) * 2, nt0 = (w >> 2) * 4;

    bf16x8 af[2][4];
#pragma unroll
    for (int m = 0; m < 2; ++m)
#pragma unroll
        for (int kc = 0; kc < 4; ++kc)
            af[m][kc] = *(const bf16x8*)&wihb[(size_t)(((mt0 + m) * 256) + kc * 64 + lane) * 8];

    f32x4 bias4[2];
#pragma unroll
    for (int m = 0; m < 2; ++m) {
        int h0 = (mt0 + m) * 16 + sub * 4;
        bias4[m] = *(const f32x4*)&bih[h0] + *(const f32x4*)&bhh[h0];
    }

    for (int tt = 0; tt < 4; ++tt) {
        int t = blockIdx.y * 4 + tt;
        int xr[4];
#pragma unroll
        for (int n = 0; n < 4; ++n)
            xr[n] = x[(size_t)(b0 + (nt0 + n) * 16 + rc) * T_ + t];

        f32x4 acc[2][4];
#pragma unroll
        for (int m = 0; m < 2; ++m)
#pragma unroll
            for (int n = 0; n < 4; ++n) acc[m][n] = (f32x4){0.f, 0.f, 0.f, 0.f};

#pragma unroll
        for (int kc = 0; kc < 4; ++kc) {
            bf16x8 bf[4];
#pragma unroll
            for (int n = 0; n < 4; ++n)
                bf[n] = *(const bf16x8*)&embb[(size_t)xr[n] * 128 + (kc * 4 + sub) * 8];
#pragma unroll
            for (int n = 0; n < 4; ++n)
#pragma unroll
                for (int m = 0; m < 2; ++m)
                    acc[m][n] = mfma16(af[m][kc], bf[n], acc[m][n]);
        }
#pragma unroll
        for (int n = 0; n < 4; ++n)
#pragma unroll
            for (int m = 0; m < 2; ++m) {
                f32x4 v = acc[m][n] + bias4[m];
                bf16x4 o;
#pragma unroll
                for (int r = 0; r < 4; ++r) o[r] = (__bf16)v[r];
                __bf16* dst = xpb + ((size_t)t * B_ + b0 + (nt0 + n) * 16 + rc) * H_
                                  + (mt0 + m) * 16 + sub * 4;
                *(bf16x4*)dst = o;
            }
    }
}

// ---------------------------------------------------------------------------
// K2: RNN scan. 64 blocks x 16 batch; 8 waves; wave w owns h rows [16w,16w+16).
// 1-term: W_hh hi-bf16 in regs; h bf16 in conflict-free granule LDS; 4
// independent depth-1 MFMAs; xt (bf16) added AFTER the MFMA tree (keeps its
// load latency off the critical path); 1 barrier/step. Final h -> hg granules.
// ---------------------------------------------------------------------------
__global__ __launch_bounds__(512, 1) void k2_rnn(
    const __bf16* __restrict__ xpb, const float* __restrict__ Whh,
    __bf16* __restrict__ hg)
{
    __shared__ __align__(16) __bf16 Hg[2][2048];
    const int tid = threadIdx.x;
    const int lane = tid & 63, w = tid >> 6;
    const int bi = blockIdx.x;
    const int b0 = bi * 16;
    const int sub = lane >> 4, c = lane & 15;

    // A fragments: W_hh rows w*16 + c (hi only); loop-invariant
    bf16x8 wah[4];
#pragma unroll
    for (int kc = 0; kc < 4; ++kc) {
        const float* src = Whh + (size_t)(w * 16 + c) * H_ + kc * 32 + sub * 8;
        f32x4 p0 = *(const f32x4*)src, p1 = *(const f32x4*)(src + 4);
        bf16x8 h8;
#pragma unroll
        for (int e = 0; e < 4; ++e) {
            h8[e] = (__bf16)p0[e];
            h8[4 + e] = (__bf16)p1[e];
        }
        wah[kc] = h8;
    }

    if (tid < 256) {
        bf16x8 z8;
#pragma unroll
        for (int e = 0; e < 8; ++e) z8[e] = (__bf16)0.0f;
        *(bf16x8*)&Hg[0][tid * 8] = z8;
    }
    __syncthreads();

    const int i0 = w * 16 + sub * 4;            // this lane's 4 hidden-out rows
    const __bf16* xb = xpb + (size_t)(b0 + c) * H_ + i0;
    const size_t xstep = (size_t)B_ * H_;
    bf16x4 xr0, xr1, xr2, xr3;
    xr0 = *(const bf16x4*)(xb);
    xr1 = *(const bf16x4*)(xb + xstep);
    xr2 = *(const bf16x4*)(xb + 2 * xstep);

    // LDS write position for hidden rows i0..i0+3, col c (granule layout)
    const int wb = (((w >> 1) * 64 + ((w & 1) * 2 + (sub >> 1)) * 16 + c) << 3)
                 + (sub & 1) * 4;

    int p = 0;
    for (int tq = 0; tq < T_; ++tq) {
        size_t tn = (tq + 3 < T_) ? (size_t)(tq + 3) : (size_t)(T_ - 1);
        xr3 = *(const bf16x4*)(xb + tn * xstep);

        const __bf16* Hp = &Hg[p][0];
        bf16x8 hb0 = *(const bf16x8*)(Hp + 0 * 512 + lane * 8);
        bf16x8 hb1 = *(const bf16x8*)(Hp + 1 * 512 + lane * 8);
        bf16x8 hb2 = *(const bf16x8*)(Hp + 2 * 512 + lane * 8);
        bf16x8 hb3 = *(const bf16x8*)(Hp + 3 * 512 + lane * 8);

        f32x4 zz = {0.f, 0.f, 0.f, 0.f};
        f32x4 a0 = mfma16(wah[0], hb0, zz);
        f32x4 a1 = mfma16(wah[1], hb1, zz);
        f32x4 a2 = mfma16(wah[2], hb2, zz);
        f32x4 a3 = mfma16(wah[3], hb3, zz);
        f32x4 s = (a0 + a1) + (a2 + a3);
        // late xt add: xr0's load latency is hidden under the MFMA tree
#pragma unroll
        for (int r = 0; r < 4; ++r) s[r] += (float)xr0[r];

        // fast tanh: 1 - 2/(exp2(2x*log2e)+1)
        bf16x4 h4;
#pragma unroll
        for (int r = 0; r < 4; ++r) {
            float e;
            asm("v_exp_f32 %0, %1" : "=v"(e) : "v"(s[r] * 2.8853900817779268f));
            float ep1 = e + 1.0f;
            float rcp;
            asm("v_rcp_f32 %0, %1" : "=v"(rcp) : "v"(ep1));
            float h = 1.0f - 2.0f * rcp;
            h4[r] = (__bf16)h;
        }
        if (tq == T_ - 1)
            *(bf16x4*)&hg[(size_t)(bi >> 3) * 16384 + (bi & 7) * 2048 + wb] = h4;

        *(bf16x4*)&Hg[p ^ 1][wb] = h4;

        asm volatile("s_waitcnt lgkmcnt(0)" ::: "memory");
        __builtin_amdgcn_s_barrier();
        __builtin_amdgcn_sched_barrier(0);
        p ^= 1;
        xr0 = xr1; xr1 = xr2; xr2 = xr3;
    }
}

// ---------------------------------------------------------------------------
// K3: out[b][v] = h[b] @ W_fc[v]^T + b_fc[v]. LDS-free, 1-term; A from wfcb
// (or cvt from f32 Wfc if wfcb==nullptr), B from hg granules.
// grid (250, 8), 512 thr.
// ---------------------------------------------------------------------------
__global__ __launch_bounds__(512, 4) void k3_head(
    const __bf16* __restrict__ wfcb, const float* __restrict__ Wfc,
    const __bf16* __restrict__ hg, const float* __restrict__ bfc,
    float* __restrict__ out)
{
    const int tid = threadIdx.x;
    const int lane = tid & 63, w = tid >> 6;
    const int gv = blockIdx.x, bt = blockIdx.y;
    const int v0 = gv * 128, b0 = bt * 128;
    const int sub = lane >> 4, rc = lane & 15;
    const int mt0 = (w & 3) * 2, nt0 = (w >> 2) * 4;

    bf16x8 af[2][4];
    if (wfcb != nullptr) {
#pragma unroll
        for (int m = 0; m < 2; ++m)
#pragma unroll
            for (int kc = 0; kc < 4; ++kc)
                af[m][kc] = *(const bf16x8*)&wfcb[(size_t)gv * 16384
                              + (size_t)(((mt0 + m) * 256) + kc * 64 + lane) * 8];
    } else {
#pragma unroll
        for (int m = 0; m < 2; ++m)
#pragma unroll
            for (int kc = 0; kc < 4; ++kc) {
                int row = v0 + (mt0 + m) * 16 + rc;
                const float* src = Wfc + (size_t)row * H_ + (kc * 4 + sub) * 8;
                f32x4 p0 = *(const f32x4*)src, p1 = *(const f32x4*)(src + 4);
                bf16x8 h8;
#pragma unroll
                for (int e = 0; e < 4; ++e) {
                    h8[e] = (__bf16)p0[e];
                    h8[4 + e] = (__bf16)p1[e];
                }
                af[m][kc] = h8;
            }
    }

    f32x4 acc[2][4];
#pragma unroll
    for (int m = 0; m < 2; ++m)
#pragma unroll
        for (int n = 0; n < 4; ++n) acc[m][n] = (f32x4){0.f, 0.f, 0.f, 0.f};

#pragma unroll
    for (int kc = 0; kc < 4; ++kc) {
        bf16x8 bf[4];
#pragma unroll
        for (int n = 0; n < 4; ++n)
            bf[n] = *(const bf16x8*)&hg[(size_t)bt * 16384
                      + (size_t)(((nt0 + n) * 256) + kc * 64 + lane) * 8];
#pragma unroll
        for (int n = 0; n < 4; ++n)
#pragma unroll
            for (int m = 0; m < 2; ++m)
                acc[m][n] = mfma16(af[m][kc], bf[n], acc[m][n]);
    }
    f32x4 bias4[2];
#pragma unroll
    for (int m = 0; m < 2; ++m)
        bias4[m] = *(const f32x4*)&bfc[v0 + (mt0 + m) * 16 + sub * 4];
#pragma unroll
    for (int n = 0; n < 4; ++n)
#pragma unroll
        for (int m = 0; m < 2; ++m) {
            f32x4 v = acc[m][n] + bias4[m];
            float* dst = out + (size_t)(b0 + (nt0 + n) * 16 + rc) * V_
                             + v0 + (mt0 + m) * 16 + sub * 4;
            *(f32x4*)dst = v;
        }
}

extern "C" void kernel_launch(void* const* d_in, const int* in_sizes, int n_in,
                              void* d_out, int out_size, void* d_ws, size_t ws_size,
                              hipStream_t stream) {
    const int*   x   = (const int*)d_in[0];
    const float* emb = (const float*)d_in[1];
    const float* Wih = (const float*)d_in[2];
    const float* Whh = (const float*)d_in[3];
    const float* bih = (const float*)d_in[4];
    const float* bhh = (const float*)d_in[5];
    const float* Wfc = (const float*)d_in[6];
    const float* bfc = (const float*)d_in[7];
    float* out = (float*)d_out;

    const size_t SZ_HG   = 262144;      // 8 x 16384 bf16
    const size_t SZ_WIHB = 32768;
    const size_t SZ_EMBB = (size_t)V_ * 128 * 2;        // 8.192 MB
    const size_t SZ_WFCB = (size_t)V_ * 128 * 2;        // 8.192 MB
    const size_t SZ_XPB  = (size_t)T_ * B_ * H_ * 2;    // 64 MB

    char* wsb = (char*)d_ws;
    size_t off = 0;
    auto take = [&](size_t n) -> char* {
        char* p = wsb + off;
        off += (n + 255) & ~(size_t)255;
        return p;
    };
    char* outb = (char*)d_out;
    size_t ooff = 0;
    auto takeOut = [&](size_t n) -> char* {
        char* p = outb + ooff;
        ooff += (n + 255) & ~(size_t)255;
        return p;
    };
    auto fits = [&](size_t n) { return off + n + 256 <= ws_size; };

    __bf16* hgp   = (__bf16*)take(SZ_HG);     // required in ws
    __bf16* wihb  = (__bf16*)take(SZ_WIHB);   // required in ws
    __bf16* wfcb  = nullptr;                  // must be in ws (K3 reads during out write)
    if (fits(SZ_WFCB)) wfcb = (__bf16*)take(SZ_WFCB);
    __bf16* embb  = fits(SZ_EMBB) ? (__bf16*)take(SZ_EMBB) : (__bf16*)takeOut(SZ_EMBB);
    __bf16* xpb   = fits(SZ_XPB)  ? (__bf16*)take(SZ_XPB)  : (__bf16*)takeOut(SZ_XPB);

    k0_emb<<<4000, 256, 0, stream>>>(emb, embb);
    k0_wih<<<1, 512, 0, stream>>>(Wih, wihb);
    if (wfcb) k0_wfc<<<250, 512, 0, stream>>>(Wfc, wfcb);

    k1_xproj<<<dim3(8, 64), 512, 0, stream>>>(x, embb, wihb, bih, bhh, xpb);
    k2_rnn<<<dim3(64), 512, 0, stream>>>(xpb, Whh, hgp);
    k3_head<<<dim3(250, 8), 512, 0, stream>>>(wfcb, Wfc, hgp, bfc, out);
}

// Round 6
// 205.777 us; speedup vs baseline: 1.4820x; 1.0000x over previous
//
#include <hip/hip_runtime.h>
#include <hip/hip_bf16.h>

#define V_ 32000
#define E_ 100
#define H_ 128
#define B_ 1024
#define T_ 256

typedef float f32x4 __attribute__((ext_vector_type(4)));
typedef __bf16 bf16x8 __attribute__((ext_vector_type(8)));
typedef __bf16 bf16x4 __attribute__((ext_vector_type(4)));

__device__ __forceinline__ f32x4 mfma16(bf16x8 a, bf16x8 b, f32x4 c) {
    return __builtin_amdgcn_mfma_f32_16x16x32_bf16(a, b, c, 0, 0, 0);
}

// Granule layout (per 128x128 matrix): granule g holds elements
// [row = (g>>8)*16 + (g&15)][k = ((g>>4)&15)*8 .. +8), stored at elems g*8.
// MFMA frag read for (tile,kc) at lane l: elem off tile*2048 + kc*512 + l*8.

// ---------------------------------------------------------------------------
// K0a: embb[v][k] = bf16(emb[v][k]) zero-padded K 100->128.  grid 4000x256.
// ---------------------------------------------------------------------------
__global__ void k0_emb(const float* __restrict__ emb, __bf16* __restrict__ embb) {
    int i = blockIdx.x * 256 + threadIdx.x;      // one bf16x4 per thread
    int e4 = i * 4;
    int v = e4 >> 7, k = e4 & 127;
    if (v >= V_) return;
    bf16x4 o;
    if (k < E_) {
        f32x4 p = *(const f32x4*)&emb[(size_t)v * E_ + k];
#pragma unroll
        for (int r = 0; r < 4; ++r) o[r] = (__bf16)p[r];
    } else {
#pragma unroll
        for (int r = 0; r < 4; ++r) o[r] = (__bf16)0.0f;
    }
    *(bf16x4*)&embb[(size_t)v * 128 + k] = o;
}

// ---------------------------------------------------------------------------
// K0b: W_ih (128x100 f32) -> granule-layout bf16 (K padded to 128). 1 block.
// ---------------------------------------------------------------------------
__global__ void k0_wih(const float* __restrict__ Wih, __bf16* __restrict__ wihb) {
    int tid = threadIdx.x;
#pragma unroll
    for (int i = 0; i < 4; ++i) {
        int t2 = tid + i * 512;
        int tile = t2 >> 8, row4 = (t2 >> 4) & 15, ch = t2 & 15;
        int grow = tile * 16 + row4;
        int g = tile * 256 + ch * 16 + row4;
        bf16x8 o;
#pragma unroll
        for (int e = 0; e < 8; ++e) {
            int k = ch * 8 + e;
            o[e] = (k < E_) ? (__bf16)Wih[(size_t)grow * E_ + k] : (__bf16)0.0f;
        }
        *(bf16x8*)&wihb[(size_t)g * 8] = o;
    }
}

// ---------------------------------------------------------------------------
// K0c: W_fc (32000x128 f32) -> 250 x granule-layout bf16. grid 250x512.
// Thread mapping gives coalesced 512B row reads.
// ---------------------------------------------------------------------------
__global__ void k0_wfc(const float* __restrict__ Wfc, __bf16* __restrict__ wfcb) {
    int gv = blockIdx.x, tid = threadIdx.x;
#pragma unroll
    for (int i = 0; i < 4; ++i) {
        int t2 = tid + i * 512;
        int tile = t2 >> 8, row4 = (t2 >> 4) & 15, ch = t2 & 15;
        int grow = gv * 128 + tile * 16 + row4;
        int g = tile * 256 + ch * 16 + row4;
        const float* src = Wfc + (size_t)grow * H_ + ch * 8;
        f32x4 p0 = *(const f32x4*)src, p1 = *(const f32x4*)(src + 4);
        bf16x8 o;
#pragma unroll
        for (int e = 0; e < 4; ++e) {
            o[e] = (__bf16)p0[e];
            o[4 + e] = (__bf16)p1[e];
        }
        *(bf16x8*)&wfcb[(size_t)gv * 16384 + g * 8] = o;
    }
}

// ---------------------------------------------------------------------------
// K1: xpb[t][b][h] = bf16(emb[x[b,t]] @ W_ih^T + b_ih + b_hh). LDS-free,
// 1-term. A=W_ih frags in regs (once); B=emb frags gathered per t.
// grid (8 batch-blocks, 64 t-blocks), 4 t per block, 512 thr.
// ---------------------------------------------------------------------------
__global__ __launch_bounds__(512, 4) void k1_xproj(
    const int* __restrict__ x, const __bf16* __restrict__ embb,
    const __bf16* __restrict__ wihb, const float* __restrict__ bih,
    const float* __restrict__ bhh, __bf16* __restrict__ xpb)
{
    const int tid = threadIdx.x;
    const int lane = tid & 63, w = tid >> 6;
    const int b0 = blockIdx.x * 128;
    const int sub = lane >> 4, rc = lane & 15;
    const int mt0 = (w & 3) * 2, nt0 = (w >> 2) * 4;

    bf16x8 af[2][4];
#pragma unroll
    for (int m = 0; m < 2; ++m)
#pragma unroll
        for (int kc = 0; kc < 4; ++kc)
            af[m][kc] = *(const bf16x8*)&wihb[(size_t)(((mt0 + m) * 256) + kc * 64 + lane) * 8];

    f32x4 bias4[2];
#pragma unroll
    for (int m = 0; m < 2; ++m) {
        int h0 = (mt0 + m) * 16 + sub * 4;
        bias4[m] = *(const f32x4*)&bih[h0] + *(const f32x4*)&bhh[h0];
    }

    for (int tt = 0; tt < 4; ++tt) {
        int t = blockIdx.y * 4 + tt;
        int xr[4];
#pragma unroll
        for (int n = 0; n < 4; ++n)
            xr[n] = x[(size_t)(b0 + (nt0 + n) * 16 + rc) * T_ + t];

        f32x4 acc[2][4];
#pragma unroll
        for (int m = 0; m < 2; ++m)
#pragma unroll
            for (int n = 0; n < 4; ++n) acc[m][n] = (f32x4){0.f, 0.f, 0.f, 0.f};

#pragma unroll
        for (int kc = 0; kc < 4; ++kc) {
            bf16x8 bf[4];
#pragma unroll
            for (int n = 0; n < 4; ++n)
                bf[n] = *(const bf16x8*)&embb[(size_t)xr[n] * 128 + (kc * 4 + sub) * 8];
#pragma unroll
            for (int n = 0; n < 4; ++n)
#pragma unroll
                for (int m = 0; m < 2; ++m)
                    acc[m][n] = mfma16(af[m][kc], bf[n], acc[m][n]);
        }
#pragma unroll
        for (int n = 0; n < 4; ++n)
#pragma unroll
            for (int m = 0; m < 2; ++m) {
                f32x4 v = acc[m][n] + bias4[m];
                bf16x4 o;
#pragma unroll
                for (int r = 0; r < 4; ++r) o[r] = (__bf16)v[r];
                __bf16* dst = xpb + ((size_t)t * B_ + b0 + (nt0 + n) * 16 + rc) * H_
                                  + (mt0 + m) * 16 + sub * 4;
                *(bf16x4*)dst = o;
            }
    }
}

// ---------------------------------------------------------------------------
// K2: RNN scan. 64 blocks x 16 batch; 8 waves; wave w owns h rows [16w,16w+16).
// 1-term: W_hh hi-bf16 in regs; h bf16 in conflict-free granule LDS; 4
// independent depth-1 MFMAs; xt (bf16) added AFTER the MFMA tree (keeps its
// load latency off the critical path); 1 barrier/step. Final h -> hg granules.
// ---------------------------------------------------------------------------
__global__ __launch_bounds__(512, 1) void k2_rnn(
    const __bf16* __restrict__ xpb, const float* __restrict__ Whh,
    __bf16* __restrict__ hg)
{
    __shared__ __align__(16) __bf16 Hg[2][2048];
    const int tid = threadIdx.x;
    const int lane = tid & 63, w = tid >> 6;
    const int bi = blockIdx.x;
    const int b0 = bi * 16;
    const int sub = lane >> 4, c = lane & 15;

    // A fragments: W_hh rows w*16 + c (hi only); loop-invariant
    bf16x8 wah[4];
#pragma unroll
    for (int kc = 0; kc < 4; ++kc) {
        const float* src = Whh + (size_t)(w * 16 + c) * H_ + kc * 32 + sub * 8;
        f32x4 p0 = *(const f32x4*)src, p1 = *(const f32x4*)(src + 4);
        bf16x8 h8;
#pragma unroll
        for (int e = 0; e < 4; ++e) {
            h8[e] = (__bf16)p0[e];
            h8[4 + e] = (__bf16)p1[e];
        }
        wah[kc] = h8;
    }

    if (tid < 256) {
        bf16x8 z8;
#pragma unroll
        for (int e = 0; e < 8; ++e) z8[e] = (__bf16)0.0f;
        *(bf16x8*)&Hg[0][tid * 8] = z8;
    }
    __syncthreads();

    const int i0 = w * 16 + sub * 4;            // this lane's 4 hidden-out rows
    const __bf16* xb = xpb + (size_t)(b0 + c) * H_ + i0;
    const size_t xstep = (size_t)B_ * H_;
    bf16x4 xr0, xr1, xr2, xr3;
    xr0 = *(const bf16x4*)(xb);
    xr1 = *(const bf16x4*)(xb + xstep);
    xr2 = *(const bf16x4*)(xb + 2 * xstep);

    // LDS write position for hidden rows i0..i0+3, col c (granule layout)
    const int wb = (((w >> 1) * 64 + ((w & 1) * 2 + (sub >> 1)) * 16 + c) << 3)
                 + (sub & 1) * 4;

    int p = 0;
    for (int tq = 0; tq < T_; ++tq) {
        size_t tn = (tq + 3 < T_) ? (size_t)(tq + 3) : (size_t)(T_ - 1);
        xr3 = *(const bf16x4*)(xb + tn * xstep);

        const __bf16* Hp = &Hg[p][0];
        bf16x8 hb0 = *(const bf16x8*)(Hp + 0 * 512 + lane * 8);
        bf16x8 hb1 = *(const bf16x8*)(Hp + 1 * 512 + lane * 8);
        bf16x8 hb2 = *(const bf16x8*)(Hp + 2 * 512 + lane * 8);
        bf16x8 hb3 = *(const bf16x8*)(Hp + 3 * 512 + lane * 8);

        f32x4 zz = {0.f, 0.f, 0.f, 0.f};
        f32x4 a0 = mfma16(wah[0], hb0, zz);
        f32x4 a1 = mfma16(wah[1], hb1, zz);
        f32x4 a2 = mfma16(wah[2], hb2, zz);
        f32x4 a3 = mfma16(wah[3], hb3, zz);
        f32x4 s = (a0 + a1) + (a2 + a3);
        // late xt add: xr0's load latency is hidden under the MFMA tree
#pragma unroll
        for (int r = 0; r < 4; ++r) s[r] += (float)xr0[r];

        // fast tanh: 1 - 2/(exp2(2x*log2e)+1)
        bf16x4 h4;
#pragma unroll
        for (int r = 0; r < 4; ++r) {
            float e;
            asm("v_exp_f32 %0, %1" : "=v"(e) : "v"(s[r] * 2.8853900817779268f));
            float ep1 = e + 1.0f;
            float rcp;
            asm("v_rcp_f32 %0, %1" : "=v"(rcp) : "v"(ep1));
            float h = 1.0f - 2.0f * rcp;
            h4[r] = (__bf16)h;
        }
        if (tq == T_ - 1)
            *(bf16x4*)&hg[(size_t)(bi >> 3) * 16384 + (bi & 7) * 2048 + wb] = h4;

        *(bf16x4*)&Hg[p ^ 1][wb] = h4;

        asm volatile("s_waitcnt lgkmcnt(0)" ::: "memory");
        __builtin_amdgcn_s_barrier();
        __builtin_amdgcn_sched_barrier(0);
        p ^= 1;
        xr0 = xr1; xr1 = xr2; xr2 = xr3;
    }
}

// ---------------------------------------------------------------------------
// K3: out[b][v] = h[b] @ W_fc[v]^T + b_fc[v]. LDS-free, 1-term; A from wfcb
// (or cvt from f32 Wfc if wfcb==nullptr), B from hg granules.
// grid (250, 8), 512 thr.
// ---------------------------------------------------------------------------
__global__ __launch_bounds__(512, 4) void k3_head(
    const __bf16* __restrict__ wfcb, const float* __restrict__ Wfc,
    const __bf16* __restrict__ hg, const float* __restrict__ bfc,
    float* __restrict__ out)
{
    const int tid = threadIdx.x;
    const int lane = tid & 63, w = tid >> 6;
    const int gv = blockIdx.x, bt = blockIdx.y;
    const int v0 = gv * 128, b0 = bt * 128;
    const int sub = lane >> 4, rc = lane & 15;
    const int mt0 = (w & 3) * 2, nt0 = (w >> 2) * 4;

    bf16x8 af[2][4];
    if (wfcb != nullptr) {
#pragma unroll
        for (int m = 0; m < 2; ++m)
#pragma unroll
            for (int kc = 0; kc < 4; ++kc)
                af[m][kc] = *(const bf16x8*)&wfcb[(size_t)gv * 16384
                              + (size_t)(((mt0 + m) * 256) + kc * 64 + lane) * 8];
    } else {
#pragma unroll
        for (int m = 0; m < 2; ++m)
#pragma unroll
            for (int kc = 0; kc < 4; ++kc) {
                int row = v0 + (mt0 + m) * 16 + rc;
                const float* src = Wfc + (size_t)row * H_ + (kc * 4 + sub) * 8;
                f32x4 p0 = *(const f32x4*)src, p1 = *(const f32x4*)(src + 4);
                bf16x8 h8;
#pragma unroll
                for (int e = 0; e < 4; ++e) {
                    h8[e] = (__bf16)p0[e];
                    h8[4 + e] = (__bf16)p1[e];
                }
                af[m][kc] = h8;
            }
    }

    f32x4 acc[2][4];
#pragma unroll
    for (int m = 0; m < 2; ++m)
#pragma unroll
        for (int n = 0; n < 4; ++n) acc[m][n] = (f32x4){0.f, 0.f, 0.f, 0.f};

#pragma unroll
    for (int kc = 0; kc < 4; ++kc) {
        bf16x8 bf[4];
#pragma unroll
        for (int n = 0; n < 4; ++n)
            bf[n] = *(const bf16x8*)&hg[(size_t)bt * 16384
                      + (size_t)(((nt0 + n) * 256) + kc * 64 + lane) * 8];
#pragma unroll
        for (int n = 0; n < 4; ++n)
#pragma unroll
            for (int m = 0; m < 2; ++m)
                acc[m][n] = mfma16(af[m][kc], bf[n], acc[m][n]);
    }
    f32x4 bias4[2];
#pragma unroll
    for (int m = 0; m < 2; ++m)
        bias4[m] = *(const f32x4*)&bfc[v0 + (mt0 + m) * 16 + sub * 4];
#pragma unroll
    for (int n = 0; n < 4; ++n)
#pragma unroll
        for (int m = 0; m < 2; ++m) {
            f32x4 v = acc[m][n] + bias4[m];
            float* dst = out + (size_t)(b0 + (nt0 + n) * 16 + rc) * V_
                             + v0 + (mt0 + m) * 16 + sub * 4;
            *(f32x4*)dst = v;
        }
}

extern "C" void kernel_launch(void* const* d_in, const int* in_sizes, int n_in,
                              void* d_out, int out_size, void* d_ws, size_t ws_size,
                              hipStream_t stream) {
    const int*   x   = (const int*)d_in[0];
    const float* emb = (const float*)d_in[1];
    const float* Wih = (const float*)d_in[2];
    const float* Whh = (const float*)d_in[3];
    const float* bih = (const float*)d_in[4];
    const float* bhh = (const float*)d_in[5];
    const float* Wfc = (const float*)d_in[6];
    const float* bfc = (const float*)d_in[7];
    float* out = (float*)d_out;

    const size_t SZ_HG   = 262144;      // 8 x 16384 bf16
    const size_t SZ_WIHB = 32768;
    const size_t SZ_EMBB = (size_t)V_ * 128 * 2;        // 8.192 MB
    const size_t SZ_WFCB = (size_t)V_ * 128 * 2;        // 8.192 MB
    const size_t SZ_XPB  = (size_t)T_ * B_ * H_ * 2;    // 64 MB

    char* wsb = (char*)d_ws;
    size_t off = 0;
    auto take = [&](size_t n) -> char* {
        char* p = wsb + off;
        off += (n + 255) & ~(size_t)255;
        return p;
    };
    char* outb = (char*)d_out;
    size_t ooff = 0;
    auto takeOut = [&](size_t n) -> char* {
        char* p = outb + ooff;
        ooff += (n + 255) & ~(size_t)255;
        return p;
    };
    auto fits = [&](size_t n) { return off + n + 256 <= ws_size; };

    __bf16* hgp   = (__bf16*)take(SZ_HG);     // required in ws
    __bf16* wihb  = (__bf16*)take(SZ_WIHB);   // required in ws
    __bf16* wfcb  = nullptr;                  // must be in ws (K3 reads during out write)
    if (fits(SZ_WFCB)) wfcb = (__bf16*)take(SZ_WFCB);
    __bf16* embb  = fits(SZ_EMBB) ? (__bf16*)take(SZ_EMBB) : (__bf16*)takeOut(SZ_EMBB);
    __bf16* xpb   = fits(SZ_XPB)  ? (__bf16*)take(SZ_XPB)  : (__bf16*)takeOut(SZ_XPB);

    k0_emb<<<4000, 256, 0, stream>>>(emb, embb);
    k0_wih<<<1, 512, 0, stream>>>(Wih, wihb);
    if (wfcb) k0_wfc<<<250, 512, 0, stream>>>(Wfc, wfcb);

    k1_xproj<<<dim3(8, 64), 512, 0, stream>>>(x, embb, wihb, bih, bhh, xpb);
    k2_rnn<<<dim3(64), 512, 0, stream>>>(xpb, Whh, hgp);
    k3_head<<<dim3(250, 8), 512, 0, stream>>>(wfcb, Wfc, hgp, bfc, out);
}